// Round 12
// baseline (9962.791 us; speedup 1.0000x reference)
//
#include <hip/hip_runtime.h>

typedef __attribute__((ext_vector_type(8))) __bf16 bf16x8;
typedef __attribute__((ext_vector_type(4))) float f32x4;
typedef __attribute__((ext_vector_type(2))) float f32x2;
typedef __attribute__((ext_vector_type(4))) unsigned int u32x4;
typedef unsigned int u32;
typedef unsigned long long u64;

#define NSEQ 32
#define TTOT 2048
#define DIM  512
#define HID  512
#define G4   2048
#define NGEMM 224
#define NTILE 8192   // 512 t-slabs x 16 col-tiles
#define LEAD  96     // gemm lead window in steps
#define TAGM 0x0000ffff0000ffffull

#define AL(p)     __hip_atomic_load((p), __ATOMIC_RELAXED, __HIP_MEMORY_SCOPE_AGENT)
#define AS(p, v)  __hip_atomic_store((p), (v), __ATOMIC_RELAXED, __HIP_MEMORY_SCOPE_AGENT)
#define AX(p, v)  __hip_atomic_exchange((p), (v), __ATOMIC_RELAXED, __HIP_MEMORY_SCOPE_AGENT)

__device__ __forceinline__ float sigmoidf_(float x) {
    return 1.0f / (1.0f + __expf(-x));
}
__device__ __forceinline__ float tanhf_(float x) {
    return 2.0f / (1.0f + __expf(-2.0f * x)) - 1.0f;
}
__device__ __forceinline__ float bflo(u32 v) { return __builtin_bit_cast(float, v << 16); }
__device__ __forceinline__ float bfhi(u32 v) { return __builtin_bit_cast(float, v & 0xffff0000u); }

// ws layout:
//  WxbT  @ 0        (2 MiB)   bf16 [2048 col][512 k]
//  WhbT  @ 2 MiB    (2 MiB)   bf16 [2048 col][512 k]
//  hctag @ 4 MiB    (512 KiB) tagged ring [8 slot][2 grp][16 chunk][16 seq][16 u64]
//  doneT @ 4M+512K  (2 KiB)   u32 [512 t-slabs]  (RMW, proven)
//  recT  @ 4M+515K  (64 B)    u32 [1]            (RMW)
//  sent  @ 4M+516K  (128 B)   u32 [2 grp][16 j]  hint sentinels (no ordering role)
//  cstate@ 4M+520K  (64 KiB)
//  AxwB  @ 4M+640K  (256 MiB) bf16 [T*32 rows][2048], agent-store
//
// Protocol: sentinel = cheap DETECTION HINT (64B line poll, ~8KB/round chip-wide);
// tagged data = CORRECTNESS (per-u32 step tags). Producer fire-and-forgets tagged
// publish AND sentinel — NO vmcnt drain, NO barrier before signal (the ACK leg is
// deleted; any sentinel/data completion skew is absorbed by rare tag-retries).
// Seq-groups are independent pipelines => skew <=1 step => ring-8 safe.

// ---------------- init ----------------
__global__ void lstm_init(const float* __restrict__ Wx, const float* __restrict__ Wh,
                          const float* __restrict__ h0,
                          __bf16* __restrict__ WxbT, __bf16* __restrict__ WhbT,
                          u32* __restrict__ hctag, u32* __restrict__ doneT,
                          u32* __restrict__ recT, u32* __restrict__ sent,
                          float* __restrict__ cstate)
{
    int idx = blockIdx.x * 256 + threadIdx.x;   // 0 .. 2048*512-1
    int c = idx & (G4 - 1);
    int k = idx >> 11;
    WxbT[(size_t)c * DIM + k] = (__bf16)Wx[idx];
    WhbT[(size_t)c * HID + k] = (__bf16)Wh[idx];
    if (idx < 131072) {                         // scrub all 8 ring slots
        u32 v = 0;
        if (idx < 16384) {                      // seed slot 0 = h_0, tag 1
            int f  = idx >> 1;
            int i  = f >> 12;
            int j  = (f >> 8) & 15;
            int s  = (f >> 4) & 15;
            int cp = f & 15;
            int seq = i * 16 + s;
            int col = j * 32 + cp * 2 + (idx & 1);
            __bf16 hb = (__bf16)h0[seq * HID + col];
            v = ((u32)__builtin_bit_cast(unsigned short, hb) << 16) | 1u;
        }
        hctag[idx] = v;
    }
    if (idx < NSEQ * HID) cstate[idx] = 0.0f;
    if (idx < 512) doneT[idx] = 0;
    if (idx < 1)   recT[idx] = 0;
    if (idx < 32)  sent[idx] = 0;               // "h_0 ready"
}

// ---------------- mono kernel: blocks 0-31 recurrence, 32-255 persistent GEMM --------
__global__ __launch_bounds__(256, 1) void lstm_mono(
    const float* __restrict__ x,      // [32][2048][512] f32
    const __bf16* __restrict__ WxbT,  // [2048][512]
    const float* __restrict__ bvec,   // [2048]
    const __bf16* __restrict__ WhbT,  // [2048][512]
    u32* __restrict__ hctag,          // tagged ring
    u32* __restrict__ doneT,
    u32* __restrict__ recT,
    u32* __restrict__ sent,
    __bf16* __restrict__ AxwB,        // [65536][2048] bf16, row r = t*32+n
    float* __restrict__ cstate,
    float* __restrict__ out)          // [32][2048][512] f32
{
    const int bid  = blockIdx.x;
    const int tid  = threadIdx.x;
    const int w    = tid >> 6;
    const int lane = tid & 63;
    const int l15  = lane & 15;
    const int lq   = lane >> 4;

    __shared__ float P[2][4][16][132];   // rec only

    if (bid >= 32) {
        // ================= persistent xWx GEMM (throttled to rec progress) =========
        const int wm = w >> 1, wn = w & 1;
        for (int tile = bid - 32; tile < NTILE; tile += NGEMM) {
            const int ts = tile >> 4;          // t-slab (4 timesteps)
            const int cb = (tile & 15) * 128;
            const int m0 = ts * 128;

            // throttle: stay at most LEAD steps ahead of the recurrence
            {
                const int need = 4 * ts - LEAD;
                if (need > 0)
                    while ((int)AL(recT) < need) __builtin_amdgcn_s_sleep(8);
            }

            f32x4 acc[4][4] = {};
            const float* xrow[4];
#pragma unroll
            for (int mi = 0; mi < 4; ++mi) {
                int r = m0 + wm * 64 + mi * 16 + l15;
                int t = r >> 5, n = r & 31;
                xrow[mi] = x + ((size_t)n * TTOT + t) * DIM;
            }
            const __bf16* bcol[4];
#pragma unroll
            for (int ni = 0; ni < 4; ++ni)
                bcol[ni] = WxbT + (size_t)(cb + wn * 64 + ni * 16 + l15) * DIM;

            for (int k0 = 0; k0 < DIM; k0 += 32) {
                bf16x8 af[4], bfr[4];
#pragma unroll
                for (int mi = 0; mi < 4; ++mi) {
                    const float* p = xrow[mi] + k0 + lq * 8;
                    f32x4 f0 = *(const f32x4*)p;
                    f32x4 f1 = *(const f32x4*)(p + 4);
                    bf16x8 a;
                    a[0] = (__bf16)f0[0]; a[1] = (__bf16)f0[1]; a[2] = (__bf16)f0[2]; a[3] = (__bf16)f0[3];
                    a[4] = (__bf16)f1[0]; a[5] = (__bf16)f1[1]; a[6] = (__bf16)f1[2]; a[7] = (__bf16)f1[3];
                    af[mi] = a;
                }
#pragma unroll
                for (int ni = 0; ni < 4; ++ni)
                    bfr[ni] = *(const bf16x8*)(bcol[ni] + k0 + lq * 8);
#pragma unroll
                for (int mi = 0; mi < 4; ++mi)
#pragma unroll
                    for (int ni = 0; ni < 4; ++ni)
                        acc[mi][ni] = __builtin_amdgcn_mfma_f32_16x16x32_bf16(af[mi], bfr[ni], acc[mi][ni], 0, 0, 0);
            }

            // epilogue: bf16-pack 4 cols/u64, agent-scope STORE (no RMW flood)
#pragma unroll
            for (int ni = 0; ni < 4; ++ni) {
                int col = cb + wn * 64 + ni * 16 + l15;
                float bias = bvec[col];
#pragma unroll
                for (int mi = 0; mi < 4; ++mi) {
#pragma unroll
                    for (int jj = 0; jj < 4; ++jj) {
                        int r = m0 + wm * 64 + mi * 16 + lq * 4 + jj;
                        float f = acc[mi][ni][jj] + bias;
                        u32 hb  = (u32)__builtin_bit_cast(unsigned short, (__bf16)f);
                        u32 p01 = hb | ((u32)__shfl_xor((int)hb, 1) << 16);
                        u32 p23 = (u32)__shfl_xor((int)p01, 2);
                        if ((l15 & 3) == 0) {
                            u64 pk = (u64)p01 | ((u64)p23 << 32);
                            AS((u64*)AxwB + (((size_t)r * G4 + col) >> 2), pk);
                        }
                    }
                }
            }
            __syncthreads();   // drains all threads' stores (vmcnt) before signal
            if (tid == 0)
                __hip_atomic_fetch_add(&doneT[ts], 1u, __ATOMIC_RELAXED, __HIP_MEMORY_SCOPE_AGENT);
        }
        return;
    }

    // ================= recurrence: sentinel hint + tagged single-read =================
    const int i = bid >> 4;
    const int j = bid & 15;

    // B-frags: 8 N-tiles x 4 K-tiles (wave w owns K-tiles/chunks 4w..4w+3)
    bf16x8 bfrag[8][4];
#pragma unroll
    for (int n = 0; n < 8; ++n) {
        const __bf16* base = WhbT
            + (size_t)((n >> 1) * 512 + j * 32 + (n & 1) * 16 + l15) * HID
            + (4 * w) * 32 + lq * 8;
#pragma unroll
        for (int kk = 0; kk < 4; ++kk)
            bfrag[n][kk] = *(const bf16x8*)(base + kk * 32);
    }
#pragma unroll
    for (int n = 0; n < 8; ++n)
#pragma unroll
        for (int kk = 0; kk < 4; ++kk)
            asm volatile("" : "+v"(bfrag[n][kk]));

    const int s   = tid >> 4;
    const int cp  = tid & 15;
    const int seq = i * 16 + s;
    const int hc0 = j * 32 + 2 * cp;
    float c0 = cstate[seq * HID + hc0];
    float c1 = cstate[seq * HID + hc0 + 1];

    const u32* sp = sent + i * 16 + l15;   // this group's sentinel line
    int ok_t = -1;
    u32 pv = 0; int pv_ok = 0;

    for (int t = 0; t < TTOT; ++t) {
        // --- Axw slab gate (blocking only at startup) ---
        if (t > ok_t) {
            u32 dv;
            do { dv = AL(&doneT[t >> 2]); } while (dv < 16u);
            ok_t = t | 3;
            pv_ok = 0;
            asm volatile("" ::: "memory");
        }

        // --- Axw prefetch: 4 bypass loads (latency hidden under poll) ---
        const size_t arow = (size_t)(t * 32 + seq) * G4 + hc0;
        u32 a0 = AL((const u32*)(AxwB + arow));
        u32 a1 = AL((const u32*)(AxwB + arow + 512));
        u32 a2 = AL((const u32*)(AxwB + arow + 1024));
        u32 a3 = AL((const u32*)(AxwB + arow + 1536));

        // --- sentinel HINT poll: one 64B line, 4-deep pipelined (cheap detect) ---
        {
            int v0 = (int)AL(sp);
            int v1 = (int)AL(sp);
            int v2 = (int)AL(sp);
            int v3 = (int)AL(sp);
            while (!__all(v0 >= t)) {
                v0 = v1; v1 = v2; v2 = v3;
                v3 = (int)AL(sp);
            }
        }
        __builtin_amdgcn_sched_barrier(0);

        // --- single tagged bulk read; validate; rare concurrent reload ---
        const u64* hbase = (const u64*)hctag + (size_t)(t & 7) * 8192 + (size_t)i * 4096;
        const u32 etag = (u32)(t + 1);
        const u64 pat  = (u64)etag | ((u64)etag << 32);
        const u64* cp0 = hbase + (size_t)(4 * w + 0) * 256 + l15 * 16 + lq * 4;
        const u64* cp1 = hbase + (size_t)(4 * w + 1) * 256 + l15 * 16 + lq * 4;
        const u64* cp2 = hbase + (size_t)(4 * w + 2) * 256 + l15 * 16 + lq * 4;
        const u64* cp3 = hbase + (size_t)(4 * w + 3) * 256 + l15 * 16 + lq * 4;

        u64 va[4][4];
#pragma unroll
        for (int e = 0; e < 4; ++e) va[0][e] = AL(cp0 + e);
#pragma unroll
        for (int e = 0; e < 4; ++e) va[1][e] = AL(cp1 + e);
#pragma unroll
        for (int e = 0; e < 4; ++e) va[2][e] = AL(cp2 + e);
#pragma unroll
        for (int e = 0; e < 4; ++e) va[3][e] = AL(cp3 + e);
        __builtin_amdgcn_sched_barrier(0);

        {
            bool k0 = false, k1 = false, k2 = false, k3 = false;
            for (;;) {
                if (!k0) k0 = __all((((va[0][0] ^ pat) & TAGM) | ((va[0][1] ^ pat) & TAGM) |
                                     ((va[0][2] ^ pat) & TAGM) | ((va[0][3] ^ pat) & TAGM)) == 0ull);
                if (!k1) k1 = __all((((va[1][0] ^ pat) & TAGM) | ((va[1][1] ^ pat) & TAGM) |
                                     ((va[1][2] ^ pat) & TAGM) | ((va[1][3] ^ pat) & TAGM)) == 0ull);
                if (!k2) k2 = __all((((va[2][0] ^ pat) & TAGM) | ((va[2][1] ^ pat) & TAGM) |
                                     ((va[2][2] ^ pat) & TAGM) | ((va[2][3] ^ pat) & TAGM)) == 0ull);
                if (!k3) k3 = __all((((va[3][0] ^ pat) & TAGM) | ((va[3][1] ^ pat) & TAGM) |
                                     ((va[3][2] ^ pat) & TAGM) | ((va[3][3] ^ pat) & TAGM)) == 0ull);
                if (k0 && k1 && k2 && k3) break;
                if (!k0) {
#pragma unroll
                    for (int e = 0; e < 4; ++e) va[0][e] = AL(cp0 + e);
                }
                if (!k1) {
#pragma unroll
                    for (int e = 0; e < 4; ++e) va[1][e] = AL(cp1 + e);
                }
                if (!k2) {
#pragma unroll
                    for (int e = 0; e < 4; ++e) va[2][e] = AL(cp2 + e);
                }
                if (!k3) {
#pragma unroll
                    for (int e = 0; e < 4; ++e) va[3][e] = AL(cp3 + e);
                }
            }
        }

        // --- MFMA in fixed chunk order (deterministic accumulation) ---
        f32x4 acc[8] = {};
#pragma unroll
        for (int kk = 0; kk < 4; ++kk) {
            u32 q0 = ((u32)(va[kk][0] >> 16) & 0xffffu) | ((u32)(va[kk][0] >> 32) & 0xffff0000u);
            u32 q1 = ((u32)(va[kk][1] >> 16) & 0xffffu) | ((u32)(va[kk][1] >> 32) & 0xffff0000u);
            u32 q2 = ((u32)(va[kk][2] >> 16) & 0xffffu) | ((u32)(va[kk][2] >> 32) & 0xffff0000u);
            u32 q3 = ((u32)(va[kk][3] >> 16) & 0xffffu) | ((u32)(va[kk][3] >> 32) & 0xffff0000u);
            bf16x8 a = __builtin_bit_cast(bf16x8, (u32x4){q0, q1, q2, q3});
#pragma unroll
            for (int n = 0; n < 8; ++n)
                acc[n] = __builtin_amdgcn_mfma_f32_16x16x32_bf16(a, bfrag[n][kk], acc[n], 0, 0, 0);
        }

        // --- K-partials to LDS (parity ping-pong), single barrier per step ---
        const int par = t & 1;
#pragma unroll
        for (int n = 0; n < 8; ++n)
#pragma unroll
            for (int jj = 0; jj < 4; ++jj)
                P[par][w][lq * 4 + jj][n * 16 + l15] = acc[n][jj];
        __syncthreads();

        // --- gates ---
        f32x2 sq[4];
#pragma unroll
        for (int q = 0; q < 4; ++q) {
            f32x2 v0 = *(const f32x2*)&P[par][0][s][q * 32 + 2 * cp];
            f32x2 v1 = *(const f32x2*)&P[par][1][s][q * 32 + 2 * cp];
            f32x2 v2 = *(const f32x2*)&P[par][2][s][q * 32 + 2 * cp];
            f32x2 v3 = *(const f32x2*)&P[par][3][s][q * 32 + 2 * cp];
            sq[q].x = (v0.x + v1.x) + (v2.x + v3.x);
            sq[q].y = (v0.y + v1.y) + (v2.y + v3.y);
        }

        float i0 = sigmoidf_(sq[0].x + bflo(a0)), f0 = sigmoidf_(sq[1].x + bflo(a1));
        float o0 = sigmoidf_(sq[2].x + bflo(a2)), g0 = tanhf_(sq[3].x + bflo(a3));
        c0 = f0 * c0 + i0 * g0;
        float h0v = o0 * tanhf_(c0);
        float i1 = sigmoidf_(sq[0].y + bfhi(a0)), f1 = sigmoidf_(sq[1].y + bfhi(a1));
        float o1 = sigmoidf_(sq[2].y + bfhi(a2)), g1 = tanhf_(sq[3].y + bfhi(a3));
        c1 = f1 * c1 + i1 * g1;
        float h1v = o1 * tanhf_(c1);

        // --- publish tagged h_{t+1} (fire-and-forget) + sentinel hint (NO drain) ---
        {
            const u32 tg2 = (u32)(t + 2);
            u32 w0 = ((u32)__builtin_bit_cast(unsigned short, (__bf16)h0v) << 16) | tg2;
            u32 w1 = ((u32)__builtin_bit_cast(unsigned short, (__bf16)h1v) << 16) | tg2;
            u64 pk = (u64)w0 | ((u64)w1 << 32);
            AS((u64*)hctag + (size_t)((t + 1) & 7) * 8192
                   + (size_t)i * 4096 + (size_t)j * 256 + s * 16 + cp, pk);
        }
        asm volatile("" ::: "memory");       // program-order: data store before sentinel
        if (tid == 0)
            AS((u32*)(sent + i * 16 + j), (u32)(t + 1));

        if (bid == 0 && tid == 0)
            AX(recT, (u32)(t + 1));          // rec progress for gemm throttle

        // --- out store: off the critical path ---
        *(f32x2*)(out + ((size_t)seq * TTOT + t) * HID + hc0) = (f32x2){h0v, h1v};

        // --- doneT probe, software-pipelined (zero stall in steady state) ---
        if (pv_ok && pv >= 16u) ok_t += 4;
        {
            int ns = (ok_t + 1) >> 2;
            if (ns < 512) { pv = AL(&doneT[ns]); pv_ok = 1; }
            else pv_ok = 0;
        }
    }

    cstate[seq * HID + hc0]     = c0;
    cstate[seq * HID + hc0 + 1] = c1;
}

extern "C" void kernel_launch(void* const* d_in, const int* in_sizes, int n_in,
                              void* d_out, int out_size, void* d_ws, size_t ws_size,
                              hipStream_t stream)
{
    const float* x  = (const float*)d_in[0];
    const float* h0 = (const float*)d_in[1];
    const float* Wx = (const float*)d_in[2];
    const float* Wh = (const float*)d_in[3];
    const float* b  = (const float*)d_in[4];
    float* out = (float*)d_out;

    char* ws = (char*)d_ws;
    __bf16* WxbT   = (__bf16*)(ws);
    __bf16* WhbT   = (__bf16*)(ws + (2u << 20));
    u32*    hctag  = (u32*)(ws + (4u << 20));                      // 512 KB
    u32*    doneT  = (u32*)(ws + (4u << 20) + (512u << 10));       // 2 KB
    u32*    recT   = (u32*)(ws + (4u << 20) + (515u << 10));
    u32*    sentp  = (u32*)(ws + (4u << 20) + (516u << 10));       // 128 B
    float*  cstate = (float*)(ws + (4u << 20) + (520u << 10));     // 64 KB
    __bf16* AxwB   = (__bf16*)(ws + (4u << 20) + (640u << 10));    // 256 MiB

    lstm_init<<<dim3((G4 * DIM) / 256), dim3(256), 0, stream>>>(
        Wx, Wh, h0, WxbT, WhbT, hctag, doneT, recT, sentp, cstate);

    lstm_mono<<<dim3(256), dim3(256), 0, stream>>>(
        x, WxbT, b, WhbT, hctag, doneT, recT, sentp, AxwB, cstate, out);
}

// Round 13
// 7037.917 us; speedup vs baseline: 1.4156x; 1.4156x over previous
//
#include <hip/hip_runtime.h>

typedef __attribute__((ext_vector_type(8))) __bf16 bf16x8;
typedef __attribute__((ext_vector_type(4))) float f32x4;
typedef __attribute__((ext_vector_type(2))) float f32x2;
typedef __attribute__((ext_vector_type(4))) unsigned int u32x4;
typedef unsigned int u32;
typedef unsigned long long u64;

#define NSEQ 32
#define TTOT 2048
#define DIM  512
#define HID  512
#define G4   2048
#define NGEMM 224
#define NTILE 8192   // 512 t-slabs x 16 col-tiles
#define LEAD  16     // gemm lead window in steps (tight pacing)

#define AL(p)     __hip_atomic_load((p), __ATOMIC_RELAXED, __HIP_MEMORY_SCOPE_AGENT)
#define AS(p, v)  __hip_atomic_store((p), (v), __ATOMIC_RELAXED, __HIP_MEMORY_SCOPE_AGENT)
#define AX(p, v)  __hip_atomic_exchange((p), (v), __ATOMIC_RELAXED, __HIP_MEMORY_SCOPE_AGENT)

__device__ __forceinline__ float sigmoidf_(float x) {
    return 1.0f / (1.0f + __expf(-x));
}
__device__ __forceinline__ float tanhf_(float x) {
    return 2.0f / (1.0f + __expf(-2.0f * x)) - 1.0f;
}
__device__ __forceinline__ float bflo(u32 v) { return __builtin_bit_cast(float, v << 16); }
__device__ __forceinline__ float bfhi(u32 v) { return __builtin_bit_cast(float, v & 0xffff0000u); }

// ws layout (r9-identical):
//  WxbT  @ 0        (2 MiB)   bf16 [2048 col][512 k]
//  WhbT  @ 2 MiB    (2 MiB)   bf16 [2048 col][512 k]
//  hcomm @ 4 MiB    (256 KiB) bf16 ring [8 slot][2 grp][16 chunk][16 seq][32 col]
//  sent  @ 4M+256K  (512 B)   u32 [2 grp][16 j][4 wave]   (RMW-published, proven)
//  doneT @ 4M+257K  (2 KiB)   u32 [512 t-slabs]           (RMW)
//  recT  @ 4M+259K  (64 B)    u32 [1]                     (RMW, 1/4-step)
//  cstate@ 4M+260K  (64 KiB)
//  AxwB  @ 4M+512K  (256 MiB) bf16 [T*32 rows][2048] (row r = t*32+n), agent-store
//
// Protocol (r6/r9 family — the only measured-fast one): clean bf16 data slots;
// producer wave publishes, drains ITS vmcnt (stores ACKed at coherence point),
// then RMW-publishes its per-wave sentinel. Consumer polls 16 producer-wave
// sentinels (one 64B line) 4-deep-pipelined, then bulk-reads its A-frags once.
// Round-13 deltas vs r9: (a) LDS 84KB -> 1 block/CU (no rec/gemm CU sharing);
// (b) LEAD 16 + tid0-only recT spin (gemm traffic paced, no IF flood);
// (c) recT published every 4th step before the drain (WG0 de-straggled).

// ---------------- init ----------------
__global__ void lstm_init(const float* __restrict__ Wx, const float* __restrict__ Wh,
                          const float* __restrict__ h0,
                          __bf16* __restrict__ WxbT, __bf16* __restrict__ WhbT,
                          __bf16* __restrict__ hcomm, u32* __restrict__ sent,
                          u32* __restrict__ doneT, u32* __restrict__ recT,
                          float* __restrict__ cstate)
{
    int idx = blockIdx.x * 256 + threadIdx.x;   // 0 .. 2048*512-1
    int c = idx & (G4 - 1);
    int k = idx >> 11;
    WxbT[(size_t)c * DIM + k] = (__bf16)Wx[idx];
    WhbT[(size_t)c * HID + k] = (__bf16)Wh[idx];
    if (idx < NSEQ * HID) {                     // seed ring slot 0 = h_0
        int seq = idx >> 9, cc = idx & 511;
        int i = seq >> 4, s = seq & 15;
        hcomm[(size_t)i * 8192 + (cc >> 5) * 512 + s * 32 + (cc & 31)] = (__bf16)h0[idx];
        cstate[idx] = 0.0f;
    }
    if (idx < 128) sent[idx] = 0;
    if (idx < 512) doneT[idx] = 0;
    if (idx < 1)   recT[idx] = 0;
}

// ---------------- mono kernel: blocks 0-31 recurrence, 32-255 persistent GEMM --------
__global__ __launch_bounds__(256, 1) void lstm_mono(
    const float* __restrict__ x,      // [32][2048][512] f32
    const __bf16* __restrict__ WxbT,  // [2048][512]
    const float* __restrict__ bvec,   // [2048]
    const __bf16* __restrict__ WhbT,  // [2048][512]
    __bf16* __restrict__ hcomm,
    u32* __restrict__ sent,
    u32* __restrict__ doneT,
    u32* __restrict__ recT,
    __bf16* __restrict__ AxwB,        // [65536][2048] bf16, row r = t*32+n
    float* __restrict__ cstate,
    float* __restrict__ out)          // [32][2048][512] f32
{
    const int bid  = blockIdx.x;
    const int tid  = threadIdx.x;
    const int w    = tid >> 6;
    const int lane = tid & 63;
    const int l15  = lane & 15;
    const int lq   = lane >> 4;

    // 84 KB: two blocks (168KB) exceed 160KB LDS -> hardware-enforced 1 block/CU.
    // Rec WGs therefore never share a CU with gemm WGs (r9's co-residency regression).
    __shared__ float P[2][4][16][164];
    __shared__ int gate_s;

    if (bid >= 32) {
        // ================= persistent xWx GEMM (tightly paced to rec) =========
        const int wm = w >> 1, wn = w & 1;
        for (int tile = bid - 32; tile < NTILE; tile += NGEMM) {
            const int ts = tile >> 4;          // t-slab (4 timesteps)
            const int cb = (tile & 15) * 128;
            const int m0 = ts * 128;

            // throttle: at most LEAD steps ahead; tid0-only spin (no line-hammer)
            {
                const int need = 4 * ts - LEAD;
                if (need > 0) {
                    if (tid == 0) {
                        while ((int)AL(recT) < need) __builtin_amdgcn_s_sleep(8);
                        gate_s = 1;
                    }
                    __syncthreads();
                }
            }

            f32x4 acc[4][4] = {};
            const float* xrow[4];
#pragma unroll
            for (int mi = 0; mi < 4; ++mi) {
                int r = m0 + wm * 64 + mi * 16 + l15;
                int t = r >> 5, n = r & 31;
                xrow[mi] = x + ((size_t)n * TTOT + t) * DIM;
            }
            const __bf16* bcol[4];
#pragma unroll
            for (int ni = 0; ni < 4; ++ni)
                bcol[ni] = WxbT + (size_t)(cb + wn * 64 + ni * 16 + l15) * DIM;

            for (int k0 = 0; k0 < DIM; k0 += 32) {
                bf16x8 af[4], bfr[4];
#pragma unroll
                for (int mi = 0; mi < 4; ++mi) {
                    const float* p = xrow[mi] + k0 + lq * 8;
                    f32x4 f0 = *(const f32x4*)p;
                    f32x4 f1 = *(const f32x4*)(p + 4);
                    bf16x8 a;
                    a[0] = (__bf16)f0[0]; a[1] = (__bf16)f0[1]; a[2] = (__bf16)f0[2]; a[3] = (__bf16)f0[3];
                    a[4] = (__bf16)f1[0]; a[5] = (__bf16)f1[1]; a[6] = (__bf16)f1[2]; a[7] = (__bf16)f1[3];
                    af[mi] = a;
                }
#pragma unroll
                for (int ni = 0; ni < 4; ++ni)
                    bfr[ni] = *(const bf16x8*)(bcol[ni] + k0 + lq * 8);
#pragma unroll
                for (int mi = 0; mi < 4; ++mi)
#pragma unroll
                    for (int ni = 0; ni < 4; ++ni)
                        acc[mi][ni] = __builtin_amdgcn_mfma_f32_16x16x32_bf16(af[mi], bfr[ni], acc[mi][ni], 0, 0, 0);
            }

            // epilogue: bf16-pack 4 cols/u64, agent-scope STORE (no RMW flood)
#pragma unroll
            for (int ni = 0; ni < 4; ++ni) {
                int col = cb + wn * 64 + ni * 16 + l15;
                float bias = bvec[col];
#pragma unroll
                for (int mi = 0; mi < 4; ++mi) {
#pragma unroll
                    for (int jj = 0; jj < 4; ++jj) {
                        int r = m0 + wm * 64 + mi * 16 + lq * 4 + jj;
                        float f = acc[mi][ni][jj] + bias;
                        u32 hb  = (u32)__builtin_bit_cast(unsigned short, (__bf16)f);
                        u32 p01 = hb | ((u32)__shfl_xor((int)hb, 1) << 16);
                        u32 p23 = (u32)__shfl_xor((int)p01, 2);
                        if ((l15 & 3) == 0) {
                            u64 pk = (u64)p01 | ((u64)p23 << 32);
                            AS((u64*)AxwB + (((size_t)r * G4 + col) >> 2), pk);
                        }
                    }
                }
            }
            __syncthreads();   // drains all threads' stores (vmcnt) before signal
            if (tid == 0)
                __hip_atomic_fetch_add(&doneT[ts], 1u, __ATOMIC_RELAXED, __HIP_MEMORY_SCOPE_AGENT);
        }
        return;
    }

    // ================= recurrence =================
    const int i = bid >> 4;
    const int j = bid & 15;

    // B-frags: 8 N-tiles x 4 K-tiles (wave w owns K-tiles/chunks 4w..4w+3)
    bf16x8 bfrag[8][4];
#pragma unroll
    for (int n = 0; n < 8; ++n) {
        const __bf16* base = WhbT
            + (size_t)((n >> 1) * 512 + j * 32 + (n & 1) * 16 + l15) * HID
            + (4 * w) * 32 + lq * 8;
#pragma unroll
        for (int kk = 0; kk < 4; ++kk)
            bfrag[n][kk] = *(const bf16x8*)(base + kk * 32);
    }
#pragma unroll
    for (int n = 0; n < 8; ++n)
#pragma unroll
        for (int kk = 0; kk < 4; ++kk)
            asm volatile("" : "+v"(bfrag[n][kk]));

    const int s   = tid >> 4;
    const int cp  = tid & 15;
    const int seq = i * 16 + s;
    const int hc0 = j * 32 + 2 * cp;
    float c0 = cstate[seq * HID + hc0];
    float c1 = cstate[seq * HID + hc0 + 1];

    const u32* sw = sent + i * 64 + 16 * w;   // this wave's 16 producer sentinels
    int ok_t = -1;
    u32 pv = 0; int pv_ok = 0;

    for (int t = 0; t < TTOT; ++t) {
        // --- Axw slab gate (blocking only at startup) ---
        if (t > ok_t) {
            u32 dv;
            do { dv = AL(&doneT[t >> 2]); } while (dv < 16u);
            ok_t = t | 3;
            pv_ok = 0;
            asm volatile("" ::: "memory");
        }

        // --- Axw prefetch: 4 bypass loads (latency hidden under spin) ---
        const size_t arow = (size_t)(t * 32 + seq) * G4 + hc0;
        u32 a0 = AL((const u32*)(AxwB + arow));
        u32 a1 = AL((const u32*)(AxwB + arow + 512));
        u32 a2 = AL((const u32*)(AxwB + arow + 1024));
        u32 a3 = AL((const u32*)(AxwB + arow + 1536));

        // --- sentinel spin: wave-specific window, 4-deep pipelined polls ---
        {
            int v0 = (int)AL(&sw[l15]);
            int v1 = (int)AL(&sw[l15]);
            int v2 = (int)AL(&sw[l15]);
            int v3 = (int)AL(&sw[l15]);
            while (!__all(v0 >= t)) {
                v0 = v1; v1 = v2; v2 = v3;
                v3 = (int)AL(&sw[l15]);
            }
        }
        asm volatile("" ::: "memory");
        __builtin_amdgcn_sched_barrier(0);

        // --- bulk h read: 8 u64 bypass loads = wave's A-frags ---
        const u64* slotr = (const u64*)hcomm + (size_t)(t & 7) * 4096 + (size_t)i * 2048;
        u64 d[4][2];
#pragma unroll
        for (int kk = 0; kk < 4; ++kk) {
            const u64* p = slotr + (size_t)(4 * w + kk) * 128 + l15 * 8 + lq * 2;
            d[kk][0] = AL(p);
            d[kk][1] = AL(p + 1);
        }

        f32x4 acc[8] = {};
#pragma unroll
        for (int kk = 0; kk < 4; ++kk) {
            u32x4 q = { (u32)d[kk][0], (u32)(d[kk][0] >> 32),
                        (u32)d[kk][1], (u32)(d[kk][1] >> 32) };
            bf16x8 a = __builtin_bit_cast(bf16x8, q);
#pragma unroll
            for (int n = 0; n < 8; ++n)
                acc[n] = __builtin_amdgcn_mfma_f32_16x16x32_bf16(a, bfrag[n][kk], acc[n], 0, 0, 0);
        }

        // --- K-partials to LDS (parity ping-pong), single barrier per step ---
        const int par = t & 1;
#pragma unroll
        for (int n = 0; n < 8; ++n)
#pragma unroll
            for (int jj = 0; jj < 4; ++jj)
                P[par][w][lq * 4 + jj][n * 16 + l15] = acc[n][jj];
        __syncthreads();

        // --- gates ---
        f32x2 sq[4];
#pragma unroll
        for (int q = 0; q < 4; ++q) {
            f32x2 v0 = *(const f32x2*)&P[par][0][s][q * 32 + 2 * cp];
            f32x2 v1 = *(const f32x2*)&P[par][1][s][q * 32 + 2 * cp];
            f32x2 v2 = *(const f32x2*)&P[par][2][s][q * 32 + 2 * cp];
            f32x2 v3 = *(const f32x2*)&P[par][3][s][q * 32 + 2 * cp];
            sq[q].x = (v0.x + v1.x) + (v2.x + v3.x);
            sq[q].y = (v0.y + v1.y) + (v2.y + v3.y);
        }

        float i0 = sigmoidf_(sq[0].x + bflo(a0)), f0 = sigmoidf_(sq[1].x + bflo(a1));
        float o0 = sigmoidf_(sq[2].x + bflo(a2)), g0 = tanhf_(sq[3].x + bflo(a3));
        c0 = f0 * c0 + i0 * g0;
        float h0v = o0 * tanhf_(c0);
        float i1 = sigmoidf_(sq[0].y + bfhi(a0)), f1 = sigmoidf_(sq[1].y + bfhi(a1));
        float o1 = sigmoidf_(sq[2].y + bfhi(a2)), g1 = tanhf_(sq[3].y + bfhi(a3));
        c1 = f1 * c1 + i1 * g1;
        float h1v = o1 * tanhf_(c1);

        // --- publish h_{t+1}: agent-scope store, then per-wave drain + sentinel ---
        {
            u32 v01 = (u32)__builtin_bit_cast(unsigned short, (__bf16)h0v)
                    | ((u32)__builtin_bit_cast(unsigned short, (__bf16)h1v) << 16);
            u32 prt = (u32)__shfl_xor((int)v01, 1);
            if (!(cp & 1)) {
                u64 pk = (u64)v01 | ((u64)prt << 32);
                AS((u64*)hcomm + (size_t)((t + 1) & 7) * 4096
                       + (size_t)i * 2048 + (size_t)j * 128 + s * 8 + (cp >> 1), pk);
            }
        }
        // rec progress for gemm throttle: every 4th step, overlapped with the drain
        if (bid == 0 && tid == 0 && (t & 3) == 0)
            AX(recT, (u32)(t + 1));
        asm volatile("s_waitcnt vmcnt(0)" ::: "memory");   // this wave's stores ACKed
        if (lane == 0)
            AX(&sent[i * 64 + j * 4 + w], (u32)(t + 1));   // proven RMW path

        // --- out store: off the critical path ---
        *(f32x2*)(out + ((size_t)seq * TTOT + t) * HID + hc0) = (f32x2){h0v, h1v};

        // --- doneT probe, software-pipelined (zero stall in steady state) ---
        if (pv_ok && pv >= 16u) ok_t += 4;
        {
            int ns = (ok_t + 1) >> 2;
            if (ns < 512) { pv = AL(&doneT[ns]); pv_ok = 1; }
            else pv_ok = 0;
        }
    }

    cstate[seq * HID + hc0]     = c0;
    cstate[seq * HID + hc0 + 1] = c1;
}

extern "C" void kernel_launch(void* const* d_in, const int* in_sizes, int n_in,
                              void* d_out, int out_size, void* d_ws, size_t ws_size,
                              hipStream_t stream)
{
    const float* x  = (const float*)d_in[0];
    const float* h0 = (const float*)d_in[1];
    const float* Wx = (const float*)d_in[2];
    const float* Wh = (const float*)d_in[3];
    const float* b  = (const float*)d_in[4];
    float* out = (float*)d_out;

    char* ws = (char*)d_ws;
    __bf16* WxbT   = (__bf16*)(ws);
    __bf16* WhbT   = (__bf16*)(ws + (2u << 20));
    __bf16* hcomm  = (__bf16*)(ws + (4u << 20));
    u32*    sent   = (u32*)(ws + (4u << 20) + (256u << 10));
    u32*    doneT  = (u32*)(ws + (4u << 20) + (257u << 10));
    u32*    recT   = (u32*)(ws + (4u << 20) + (259u << 10));
    float*  cstate = (float*)(ws + (4u << 20) + (260u << 10));
    __bf16* AxwB   = (__bf16*)(ws + (4u << 20) + (512u << 10));

    lstm_init<<<dim3((G4 * DIM) / 256), dim3(256), 0, stream>>>(
        Wx, Wh, h0, WxbT, WhbT, hcomm, sent, doneT, recT, cstate);

    lstm_mono<<<dim3(256), dim3(256), 0, stream>>>(
        x, WxbT, b, WhbT, hcomm, sent, doneT, recT, AxwB, cstate, out);
}